// Round 15
// baseline (389.662 us; speedup 1.0000x reference)
//
#include <hip/hip_runtime.h>
#include <float.h>
#include <math.h>

#define NN 8192
#define DH 256
#define KNN 10
#define TSTEPS 10
#define EPSC 0.1f
#define CTILE 1024          // candidates staged in LDS per tile
#define QPB 16              // queries per block (16 waves of 64)

typedef short s8v __attribute__((ext_vector_type(8)));
typedef float f4v __attribute__((ext_vector_type(4)));

__device__ __forceinline__ float bf2f(unsigned short u) {
    union { unsigned u; float f; } c; c.u = ((unsigned)u) << 16; return c.f;
}
__device__ __forceinline__ unsigned short f2bf(float f) {
    union { float f; unsigned u; } c; c.f = f;
    unsigned r = c.u + 0x7FFF + ((c.u >> 16) & 1);
    return (unsigned short)(r >> 16);
}

// -------- conv_ws [3][256][256] (k,n) -> FRAGMENT-MAJOR bf16 Wt ---------------
// frag = (kc*2+ks)*16 + nb. Lane layout matches the MFMA B operand exactly;
// a wave's B load = 1KB contiguous (fully coalesced), no LDS staging needed.
__global__ void prep_wt(const float* __restrict__ W, unsigned short* __restrict__ Wt) {
    int e = blockIdx.x * 256 + threadIdx.x;     // 768*256 = 196608
    int i8 = e & 7, lane = (e >> 3) & 63, nb = (e >> 9) & 15;
    int ks = (e >> 13) & 1, kc2 = (e >> 14) & 3, g = e >> 16;
    int quad = lane >> 4, l15 = lane & 15;
    int k = kc2 * 64 + ks * 32 + quad * 8 + i8;
    int n = nb * 16 + l15;
    Wt[e] = f2bf(W[g * 65536 + k * 256 + n]);
}

// ---------------- pos4[j] = {x, y, z, |p|^2} ----------------------------------
__global__ void prep_pos(const float* __restrict__ pos, float4* __restrict__ pos4) {
    int j = blockIdx.x * 256 + threadIdx.x;
    float x = pos[j * 3], y = pos[j * 3 + 1], z = pos[j * 3 + 2];
    float4 v; v.x = x; v.y = y; v.z = z; v.w = x * x + y * y + z * z;
    pos4[j] = v;
}

// ---------------- kNN: 1 wave/query, 16 queries/block, DPP-insert pops --------
// R14 version (~56us, structural floor for brute-force scan). Parked.
__launch_bounds__(1024)
__global__ void knn_wave(const float* __restrict__ pos, const float4* __restrict__ pos4,
                         int* __restrict__ nbr) {
    __shared__ float4 cand[CTILE];
    int tid = threadIdx.x;
    int wv = tid >> 6, lane = tid & 63;
    int i = blockIdx.x * QPB + wv;               // query for this wave
    float xi = pos[i * 3], yi = pos[i * 3 + 1], zi = pos[i * 3 + 2];
    float sqi = xi * xi + yi * yi + zi * zi;
    int igrp = i & ~63;                          // the only 64-group containing i

    float b  = FLT_MAX;                          // rank 'lane' distance
    int   ib = -1;                               // rank 'lane' index
    float thr = FLT_MAX;                         // batch-level 10th best bound

    for (int tile = 0; tile < NN / CTILE; ++tile) {
        __syncthreads();
        cand[tid] = pos4[tile * CTILE + tid];    // 1024 threads, 1 float4 each
        __syncthreads();
#pragma unroll 4
        for (int u = 0; u < CTILE / 64; ++u) {
            int jgrp = tile * CTILE + u * 64;
            float4 c = cand[u * 64 + lane];
            int j = jgrp + lane;
            float m = c.x * xi + c.y * yi + c.z * zi;
            float d = (sqi + c.w) - 2.0f * m;
            if (jgrp == igrp) {                  // wave-uniform branch
                if (j == i) d = FLT_MAX;         // self-exclusion, one batch only
            }
            unsigned long long mask = __ballot(d < thr);
            if (mask) {
                do {
                    int l = __ffsll((unsigned long long)mask) - 1;
                    mask &= mask - 1;
                    float dc = __int_as_float(__builtin_amdgcn_readlane(__float_as_int(d), l));
                    int jc = __builtin_amdgcn_readlane(j, l);
                    // shift-down neighbors via DPP row_shr:1 (lane r <- r-1)
                    float bp = __int_as_float(__builtin_amdgcn_update_dpp(
                        0, __float_as_int(b), 0x111, 0xF, 0xF, true));
                    int ip = __builtin_amdgcn_update_dpp(0, ib, 0x111, 0xF, 0xF, true);
                    bool c0 = dc < b;                    // insert at/below my rank
                    bool cp = (lane != 0) && (dc < bp);  // insert strictly below
                    b  = c0 ? (cp ? bp : dc) : b;
                    ib = c0 ? (cp ? ip : jc) : ib;
                } while (mask);
                thr = __int_as_float(__builtin_amdgcn_readlane(__float_as_int(b), 9));
            }
        }
    }
    if (lane < KNN) nbr[i * KNN + lane] = ib;    // rank r already in lane r
}

// ---------------- h = lm@emb_w + emb_b ; x = h@rw + rb ------------------------
__global__ void emb_kernel(const float* __restrict__ lm, const float* __restrict__ ew,
                           const float* __restrict__ eb, const float* __restrict__ rw,
                           const float* __restrict__ rb,
                           float* __restrict__ hdo, unsigned short* __restrict__ hbf,
                           float* __restrict__ xout) {
    __shared__ float s0[4], s1[4], s2[4];
    int i = blockIdx.x, d = threadIdx.x;
    float a0 = lm[i * 3], a1 = lm[i * 3 + 1], a2 = lm[i * 3 + 2];
    float h = eb[d] + a0 * ew[d] + a1 * ew[256 + d] + a2 * ew[512 + d];
    hdo[i * 256 + d] = h;
    hbf[i * 256 + d] = f2bf(h);
    float p0 = h * rw[d * 3], p1 = h * rw[d * 3 + 1], p2 = h * rw[d * 3 + 2];
    for (int off = 32; off; off >>= 1) {
        p0 += __shfl_down(p0, off, 64);
        p1 += __shfl_down(p1, off, 64);
        p2 += __shfl_down(p2, off, 64);
    }
    int lane = d & 63, wid = d >> 6;
    if (lane == 0) { s0[wid] = p0; s1[wid] = p1; s2[wid] = p2; }
    __syncthreads();
    if (d == 0) {
        xout[i * 3 + 0] = s0[0] + s0[1] + s0[2] + s0[3] + rb[0];
        xout[i * 3 + 1] = s1[0] + s1[1] + s1[2] + s1[3] + rb[1];
        xout[i * 3 + 2] = s2[0] + s2[1] + s2[2] + s2[3] + rb[2];
    }
}

// ---------------- hop-1: x1[i] = 0.1 * sum_{j in nbr(i)} hbf[j] ---------------
__global__ void agg_kernel(const unsigned short* __restrict__ src,
                           unsigned short* __restrict__ dst,
                           const int* __restrict__ nbr) {
    int tid = threadIdx.x;
    int slot = tid >> 5, l32 = tid & 31;
    int node = blockIdx.x * 8 + slot;
    int d0 = l32 * 8;
    const int* nb = nbr + node * KNN;
    int j[KNN];
#pragma unroll
    for (int q = 0; q < KNN; q++) j[q] = nb[q];
    uint4 v[KNN];
#pragma unroll
    for (int q = 0; q < KNN; q++) v[q] = *(const uint4*)(src + j[q] * 256 + d0);
    float a[8];
#pragma unroll
    for (int e = 0; e < 8; e++) a[e] = 0.f;
#pragma unroll
    for (int q = 0; q < KNN; q++) {
        a[0] += bf2f((unsigned short)(v[q].x & 0xffff));
        a[1] += bf2f((unsigned short)(v[q].x >> 16));
        a[2] += bf2f((unsigned short)(v[q].y & 0xffff));
        a[3] += bf2f((unsigned short)(v[q].y >> 16));
        a[4] += bf2f((unsigned short)(v[q].z & 0xffff));
        a[5] += bf2f((unsigned short)(v[q].z >> 16));
        a[6] += bf2f((unsigned short)(v[q].w & 0xffff));
        a[7] += bf2f((unsigned short)(v[q].w >> 16));
    }
    uint4 o;
    o.x = (unsigned)f2bf(a[0]*0.1f) | ((unsigned)f2bf(a[1]*0.1f) << 16);
    o.y = (unsigned)f2bf(a[2]*0.1f) | ((unsigned)f2bf(a[3]*0.1f) << 16);
    o.z = (unsigned)f2bf(a[4]*0.1f) | ((unsigned)f2bf(a[5]*0.1f) << 16);
    o.w = (unsigned)f2bf(a[6]*0.1f) | ((unsigned)f2bf(a[7]*0.1f) << 16);
    *(uint4*)(dst + node * 256 + d0) = o;
}

// ------- fused: hop-2 gather + BARRIER-FREE-K GEMM (M32, 1024 thr) ------------
// M32 x N256, 1024 threads = 16 waves, grid 256 = 1 block/CU = 4 waves/SIMD
// (same waves/SIMD as R9's best). Wave (rt=w>>3, cfg=w&7) owns rows
// [rt*16,rt*16+16) x cols [cfg*32,cfg*32+32) — each block's 384KB Wt read now
// feeds 32 rows, halving B L2 traffic 196->98MB/dispatch vs R9 at EQUAL
// occupancy (R10's M32 regression was the 2-waves/SIMD config, not the tile).
// B from fragment-major Wt (no LDS, no K-loop barriers; 2 barriers total).
// K order per output: kc 0..11, ks 0..1 ascending => bit-identical to R9.
__launch_bounds__(1024, 4)
__global__ void gemm_step(unsigned short* hbf,
                          const unsigned short* __restrict__ x1,
                          const int* __restrict__ nbr,
                          const unsigned short* __restrict__ Wt,
                          const float* __restrict__ cb,
                          const float* __restrict__ rw, const float* __restrict__ rb,
                          float* hdo, float* __restrict__ yout, float* yfin) {
    __shared__ __align__(16) short Ah[32 * 264];
    __shared__ __align__(16) short A1[32 * 264];
    __shared__ __align__(16) short X2[32 * 264];
    __shared__ float rwl[768];
    __shared__ float cbl[256];
    __shared__ float yred[16][4][4][3];    // [wave][quad][r][xyz]

    int tid = threadIdx.x;
    int m0 = blockIdx.x * 32;
    if (tid < 768) rwl[tid] = rw[tid];
    if (tid < 256) cbl[tid] = cb[tid];

    int w = tid >> 6, lane = tid & 63;
    int quad = lane >> 4, l15 = lane & 15;
    int rt = w >> 3, cfg = w & 7;
    int row = tid >> 5, cg = tid & 31;            // stage coords: 32 rows x 32 thr

    // ---- stage A for hop0 (hbf) and hop1 (x1) --------------------------------
    {
        uint4 va = *(const uint4*)(((const unsigned short*)hbf) + (m0 + row) * 256 + cg * 8);
        *(uint4*)((unsigned short*)&Ah[row * 264 + cg * 8]) = va;
        uint4 vb = *(const uint4*)(x1 + (m0 + row) * 256 + cg * 8);
        *(uint4*)((unsigned short*)&A1[row * 264 + cg * 8]) = vb;
    }
    // ---- hop-2 gather: X2[row][:] = bf16(0.1 * sum x1[nbr[row]]) -------------
    {
        const int* nb = nbr + (m0 + row) * KNN;
        int j[KNN];
#pragma unroll
        for (int q = 0; q < KNN; q++) j[q] = nb[q];
        float a[8];
#pragma unroll
        for (int e = 0; e < 8; e++) a[e] = 0.f;
#pragma unroll
        for (int q = 0; q < KNN; q++) {
            uint4 v = *(const uint4*)(x1 + j[q] * 256 + cg * 8);
            a[0] += bf2f((unsigned short)(v.x & 0xffff));
            a[1] += bf2f((unsigned short)(v.x >> 16));
            a[2] += bf2f((unsigned short)(v.y & 0xffff));
            a[3] += bf2f((unsigned short)(v.y >> 16));
            a[4] += bf2f((unsigned short)(v.z & 0xffff));
            a[5] += bf2f((unsigned short)(v.z >> 16));
            a[6] += bf2f((unsigned short)(v.w & 0xffff));
            a[7] += bf2f((unsigned short)(v.w >> 16));
        }
        uint4 o;
        o.x = (unsigned)f2bf(a[0]*0.1f) | ((unsigned)f2bf(a[1]*0.1f) << 16);
        o.y = (unsigned)f2bf(a[2]*0.1f) | ((unsigned)f2bf(a[3]*0.1f) << 16);
        o.z = (unsigned)f2bf(a[4]*0.1f) | ((unsigned)f2bf(a[5]*0.1f) << 16);
        o.w = (unsigned)f2bf(a[6]*0.1f) | ((unsigned)f2bf(a[7]*0.1f) << 16);
        *(uint4*)((unsigned short*)&X2[row * 264 + cg * 8]) = o;
    }
    __syncthreads();      // A buffers ready; K-loop is barrier-free from here

    f4v acc[2];
    acc[0] = (f4v){0.f, 0.f, 0.f, 0.f};
    acc[1] = (f4v){0.f, 0.f, 0.f, 0.f};

#pragma unroll
    for (int kc = 0; kc < 12; kc++) {
        const short* Ab = (kc < 4) ? Ah : (kc < 8) ? A1 : X2;
        int kl = (kc & 3) * 64;
#pragma unroll
        for (int ks = 0; ks < 2; ks++) {
            s8v a = *(const s8v*)(&Ab[(rt * 16 + l15) * 264 + kl + ks * 32 + quad * 8]);
#pragma unroll
            for (int f = 0; f < 2; f++) {
                // fragment-major B: one coalesced 1KB wave load
                s8v b = *(const s8v*)(Wt + ((kc * 2 + ks) * 16 + (cfg * 2 + f)) * 512 + lane * 8);
                acc[f] = __builtin_amdgcn_mfma_f32_16x16x32_bf16(a, b, acc[f], 0, 0, 0);
            }
        }
    }

    // ---- epilogue: Euler update + readout partials ---------------------------
    float py[4][3] = {};
#pragma unroll
    for (int f = 0; f < 2; f++) {
        int col = cfg * 32 + f * 16 + l15;
        float cbv = cbl[col];
        float rw0 = rwl[col * 3], rw1 = rwl[col * 3 + 1], rw2 = rwl[col * 3 + 2];
#pragma unroll
        for (int r = 0; r < 4; r++) {
            int grow = m0 + rt * 16 + quad * 4 + r;
            float cval = acc[f][r] + cbv;
            float hn = hdo[grow * 256 + col] + EPSC * tanhf(cval);
            hdo[grow * 256 + col] = hn;
            hbf[grow * 256 + col] = f2bf(hn);
            py[r][0] += hn * rw0; py[r][1] += hn * rw1; py[r][2] += hn * rw2;
        }
    }
    for (int off = 1; off < 16; off <<= 1)
        for (int r = 0; r < 4; r++)
            for (int j = 0; j < 3; j++)
                py[r][j] += __shfl_xor(py[r][j], off, 64);
    if (l15 == 0)
        for (int r = 0; r < 4; r++)
            for (int j = 0; j < 3; j++)
                yred[w][quad][r][j] = py[r][j];
    __syncthreads();
    if (w == 0 && l15 == 0) {
        for (int rt2 = 0; rt2 < 2; rt2++) {
            for (int r = 0; r < 4; r++) {
                int grow = m0 + rt2 * 16 + quad * 4 + r;
                for (int j = 0; j < 3; j++) {
                    float yv = rb[j];
                    for (int ww = rt2 * 8; ww < rt2 * 8 + 8; ww++)
                        yv += yred[ww][quad][r][j];
                    yout[grow * 3 + j] = yv;
                    if (yfin) yfin[grow * 3 + j] = yv;
                }
            }
        }
    }
}

extern "C" void kernel_launch(void* const* d_in, const int* in_sizes, int n_in,
                              void* d_out, int out_size, void* d_ws, size_t ws_size,
                              hipStream_t stream) {
    const float* lm = (const float*)d_in[0];
    const float* ew = (const float*)d_in[1];
    const float* eb = (const float*)d_in[2];
    const float* rw = (const float*)d_in[3];
    const float* rb = (const float*)d_in[4];
    const float* cw = (const float*)d_in[5];
    const float* cb = (const float*)d_in[6];

    float* out = (float*)d_out;
    float* y_out = out;
    float* h_out = out + 24576;
    float* x_out = out + 24576 + 2097152;
    float* lp_out = x_out + 24576;

    char* ws = (char*)d_ws;
    int* nbr = (int*)ws;                       ws += NN * KNN * sizeof(int);
    float4* pos4 = (float4*)ws;                ws += NN * sizeof(float4);
    char* uni = ws;
    unsigned short* hbf = (unsigned short*)uni;
    unsigned short* x1  = hbf + NN * DH;
    unsigned short* Wt  = x1 + NN * DH;

    prep_pos<<<NN / 256, 256, 0, stream>>>(lm, pos4);
    knn_wave<<<NN / QPB, 1024, 0, stream>>>(lm, pos4, nbr);
    prep_wt<<<768, 256, 0, stream>>>(cw, Wt);
    emb_kernel<<<NN, 256, 0, stream>>>(lm, ew, eb, rw, rb, h_out, hbf, x_out);
    for (int t = 0; t < TSTEPS; t++) {
        agg_kernel<<<NN / 8, 256, 0, stream>>>(hbf, x1, nbr);
        gemm_step<<<NN / 32, 1024, 0, stream>>>(hbf, x1, nbr, Wt, cb, rw, rb, h_out,
                                                lp_out + t * 24576,
                                                (t == TSTEPS - 1) ? y_out : nullptr);
    }
}

// Round 16
// 372.667 us; speedup vs baseline: 1.0456x; 1.0456x over previous
//
#include <hip/hip_runtime.h>
#include <float.h>
#include <math.h>

#define NN 8192
#define DH 256
#define KNN 10
#define TSTEPS 10
#define EPSC 0.1f
#define CTILE 1024          // candidates staged in LDS per tile
#define QPB 16              // queries per block (16 waves of 64)

typedef short s8v __attribute__((ext_vector_type(8)));
typedef float f4v __attribute__((ext_vector_type(4)));

__device__ __forceinline__ float bf2f(unsigned short u) {
    union { unsigned u; float f; } c; c.u = ((unsigned)u) << 16; return c.f;
}
__device__ __forceinline__ unsigned short f2bf(float f) {
    union { float f; unsigned u; } c; c.f = f;
    unsigned r = c.u + 0x7FFF + ((c.u >> 16) & 1);
    return (unsigned short)(r >> 16);
}

// fast tanh: (e^2x - 1)/(e^2x + 1) via v_exp_f32 + rcp. ~8 VALU vs ocml's
// ~25-50. |x| <~ 10 here (conv outputs), no overflow (needs |x|<44).
// abs err ~1e-6, x EPSC=0.1 x 10 steps -> <=1e-5 on h, vs 0.1725 threshold.
__device__ __forceinline__ float fast_tanh(float x) {
    float t = __expf(2.0f * x);
    return __fdividef(t - 1.0f, t + 1.0f);
}

// -------- conv_ws [3][256][256] (k,n) -> FRAGMENT-MAJOR bf16 Wt ---------------
// frag = (kc*2+ks)*16 + nb. Lane layout matches the MFMA B operand exactly;
// a wave's B load = 1KB contiguous (fully coalesced), no LDS staging needed.
__global__ void prep_wt(const float* __restrict__ W, unsigned short* __restrict__ Wt) {
    int e = blockIdx.x * 256 + threadIdx.x;     // 768*256 = 196608
    int i8 = e & 7, lane = (e >> 3) & 63, nb = (e >> 9) & 15;
    int ks = (e >> 13) & 1, kc2 = (e >> 14) & 3, g = e >> 16;
    int quad = lane >> 4, l15 = lane & 15;
    int k = kc2 * 64 + ks * 32 + quad * 8 + i8;
    int n = nb * 16 + l15;
    Wt[e] = f2bf(W[g * 65536 + k * 256 + n]);
}

// ---------------- pos4[j] = {x, y, z, |p|^2} ----------------------------------
__global__ void prep_pos(const float* __restrict__ pos, float4* __restrict__ pos4) {
    int j = blockIdx.x * 256 + threadIdx.x;
    float x = pos[j * 3], y = pos[j * 3 + 1], z = pos[j * 3 + 2];
    float4 v; v.x = x; v.y = y; v.z = z; v.w = x * x + y * y + z * z;
    pos4[j] = v;
}

// ---------------- kNN: 1 wave/query, 16 queries/block, DPP-insert pops --------
// R14 version (~56us, structural floor for brute-force scan). Parked.
__launch_bounds__(1024)
__global__ void knn_wave(const float* __restrict__ pos, const float4* __restrict__ pos4,
                         int* __restrict__ nbr) {
    __shared__ float4 cand[CTILE];
    int tid = threadIdx.x;
    int wv = tid >> 6, lane = tid & 63;
    int i = blockIdx.x * QPB + wv;               // query for this wave
    float xi = pos[i * 3], yi = pos[i * 3 + 1], zi = pos[i * 3 + 2];
    float sqi = xi * xi + yi * yi + zi * zi;
    int igrp = i & ~63;                          // the only 64-group containing i

    float b  = FLT_MAX;                          // rank 'lane' distance
    int   ib = -1;                               // rank 'lane' index
    float thr = FLT_MAX;                         // batch-level 10th best bound

    for (int tile = 0; tile < NN / CTILE; ++tile) {
        __syncthreads();
        cand[tid] = pos4[tile * CTILE + tid];    // 1024 threads, 1 float4 each
        __syncthreads();
#pragma unroll 4
        for (int u = 0; u < CTILE / 64; ++u) {
            int jgrp = tile * CTILE + u * 64;
            float4 c = cand[u * 64 + lane];
            int j = jgrp + lane;
            float m = c.x * xi + c.y * yi + c.z * zi;
            float d = (sqi + c.w) - 2.0f * m;
            if (jgrp == igrp) {                  // wave-uniform branch
                if (j == i) d = FLT_MAX;         // self-exclusion, one batch only
            }
            unsigned long long mask = __ballot(d < thr);
            if (mask) {
                do {
                    int l = __ffsll((unsigned long long)mask) - 1;
                    mask &= mask - 1;
                    float dc = __int_as_float(__builtin_amdgcn_readlane(__float_as_int(d), l));
                    int jc = __builtin_amdgcn_readlane(j, l);
                    // shift-down neighbors via DPP row_shr:1 (lane r <- r-1)
                    float bp = __int_as_float(__builtin_amdgcn_update_dpp(
                        0, __float_as_int(b), 0x111, 0xF, 0xF, true));
                    int ip = __builtin_amdgcn_update_dpp(0, ib, 0x111, 0xF, 0xF, true);
                    bool c0 = dc < b;                    // insert at/below my rank
                    bool cp = (lane != 0) && (dc < bp);  // insert strictly below
                    b  = c0 ? (cp ? bp : dc) : b;
                    ib = c0 ? (cp ? ip : jc) : ib;
                } while (mask);
                thr = __int_as_float(__builtin_amdgcn_readlane(__float_as_int(b), 9));
            }
        }
    }
    if (lane < KNN) nbr[i * KNN + lane] = ib;    // rank r already in lane r
}

// ---------------- h = lm@emb_w + emb_b ; x = h@rw + rb ------------------------
__global__ void emb_kernel(const float* __restrict__ lm, const float* __restrict__ ew,
                           const float* __restrict__ eb, const float* __restrict__ rw,
                           const float* __restrict__ rb,
                           float* __restrict__ hdo, unsigned short* __restrict__ hbf,
                           float* __restrict__ xout) {
    __shared__ float s0[4], s1[4], s2[4];
    int i = blockIdx.x, d = threadIdx.x;
    float a0 = lm[i * 3], a1 = lm[i * 3 + 1], a2 = lm[i * 3 + 2];
    float h = eb[d] + a0 * ew[d] + a1 * ew[256 + d] + a2 * ew[512 + d];
    hdo[i * 256 + d] = h;
    hbf[i * 256 + d] = f2bf(h);
    float p0 = h * rw[d * 3], p1 = h * rw[d * 3 + 1], p2 = h * rw[d * 3 + 2];
    for (int off = 32; off; off >>= 1) {
        p0 += __shfl_down(p0, off, 64);
        p1 += __shfl_down(p1, off, 64);
        p2 += __shfl_down(p2, off, 64);
    }
    int lane = d & 63, wid = d >> 6;
    if (lane == 0) { s0[wid] = p0; s1[wid] = p1; s2[wid] = p2; }
    __syncthreads();
    if (d == 0) {
        xout[i * 3 + 0] = s0[0] + s0[1] + s0[2] + s0[3] + rb[0];
        xout[i * 3 + 1] = s1[0] + s1[1] + s1[2] + s1[3] + rb[1];
        xout[i * 3 + 2] = s2[0] + s2[1] + s2[2] + s2[3] + rb[2];
    }
}

// ---------------- hop-1: x1[i] = 0.1 * sum_{j in nbr(i)} hbf[j] ---------------
__global__ void agg_kernel(const unsigned short* __restrict__ src,
                           unsigned short* __restrict__ dst,
                           const int* __restrict__ nbr) {
    int tid = threadIdx.x;
    int slot = tid >> 5, l32 = tid & 31;
    int node = blockIdx.x * 8 + slot;
    int d0 = l32 * 8;
    const int* nb = nbr + node * KNN;
    int j[KNN];
#pragma unroll
    for (int q = 0; q < KNN; q++) j[q] = nb[q];
    uint4 v[KNN];
#pragma unroll
    for (int q = 0; q < KNN; q++) v[q] = *(const uint4*)(src + j[q] * 256 + d0);
    float a[8];
#pragma unroll
    for (int e = 0; e < 8; e++) a[e] = 0.f;
#pragma unroll
    for (int q = 0; q < KNN; q++) {
        a[0] += bf2f((unsigned short)(v[q].x & 0xffff));
        a[1] += bf2f((unsigned short)(v[q].x >> 16));
        a[2] += bf2f((unsigned short)(v[q].y & 0xffff));
        a[3] += bf2f((unsigned short)(v[q].y >> 16));
        a[4] += bf2f((unsigned short)(v[q].z & 0xffff));
        a[5] += bf2f((unsigned short)(v[q].z >> 16));
        a[6] += bf2f((unsigned short)(v[q].w & 0xffff));
        a[7] += bf2f((unsigned short)(v[q].w >> 16));
    }
    uint4 o;
    o.x = (unsigned)f2bf(a[0]*0.1f) | ((unsigned)f2bf(a[1]*0.1f) << 16);
    o.y = (unsigned)f2bf(a[2]*0.1f) | ((unsigned)f2bf(a[3]*0.1f) << 16);
    o.z = (unsigned)f2bf(a[4]*0.1f) | ((unsigned)f2bf(a[5]*0.1f) << 16);
    o.w = (unsigned)f2bf(a[6]*0.1f) | ((unsigned)f2bf(a[7]*0.1f) << 16);
    *(uint4*)(dst + node * 256 + d0) = o;
}

// ------- fused: hop-2 gather + BARRIER-FREE-K GEMM + Euler + readout ----------
// R9/R14 exact structure (best composite): M16 x N256, 512 threads (8 waves),
// grid 512 = 2 blocks/CU = 4 waves/SIMD. B from fragment-major Wt (coalesced,
// no LDS, no K-loop barriers; 2 barriers total). R10/R15: B-traffic halving is
// ~neutral at any occupancy -> gemm is bound by shared per-row latency chains
// + epilogue VALU, not B bandwidth. This round: tanhf -> fast_tanh (exp-based,
// ~8 VALU vs ~25-50), the one phase invariant across all tried configs.
__launch_bounds__(512, 4)
__global__ void gemm_step(unsigned short* hbf,
                          const unsigned short* __restrict__ x1,
                          const int* __restrict__ nbr,
                          const unsigned short* __restrict__ Wt,
                          const float* __restrict__ cb,
                          const float* __restrict__ rw, const float* __restrict__ rb,
                          float* hdo, float* __restrict__ yout, float* yfin) {
    __shared__ __align__(16) short Ah[16 * 264];
    __shared__ __align__(16) short A1[16 * 264];
    __shared__ __align__(16) short X2[16 * 264];
    __shared__ float rwl[768];
    __shared__ float cbl[256];
    __shared__ float yred[8][4][4][3];     // [wave][quad][r][xyz]

    int tid = threadIdx.x;
    int m0 = blockIdx.x * 16;
    for (int idx = tid; idx < 768; idx += 512) rwl[idx] = rw[idx];
    if (tid < 256) cbl[tid] = cb[tid];

    int w = tid >> 6, lane = tid & 63;
    int quad = lane >> 4, l15 = lane & 15;
    int row = tid >> 5, cg = tid & 31;            // stage coords: 16 rows x 32 thr

    // ---- stage A for hop0 (hbf) and hop1 (x1) --------------------------------
    {
        uint4 va = *(const uint4*)(((const unsigned short*)hbf) + (m0 + row) * 256 + cg * 8);
        *(uint4*)((unsigned short*)&Ah[row * 264 + cg * 8]) = va;
        uint4 vb = *(const uint4*)(x1 + (m0 + row) * 256 + cg * 8);
        *(uint4*)((unsigned short*)&A1[row * 264 + cg * 8]) = vb;
    }
    // ---- hop-2 gather: X2[row][:] = bf16(0.1 * sum x1[nbr[row]]) -------------
    {
        const int* nb = nbr + (m0 + row) * KNN;
        int j[KNN];
#pragma unroll
        for (int q = 0; q < KNN; q++) j[q] = nb[q];
        float a[8];
#pragma unroll
        for (int e = 0; e < 8; e++) a[e] = 0.f;
#pragma unroll
        for (int q = 0; q < KNN; q++) {
            uint4 v = *(const uint4*)(x1 + j[q] * 256 + cg * 8);
            a[0] += bf2f((unsigned short)(v.x & 0xffff));
            a[1] += bf2f((unsigned short)(v.x >> 16));
            a[2] += bf2f((unsigned short)(v.y & 0xffff));
            a[3] += bf2f((unsigned short)(v.y >> 16));
            a[4] += bf2f((unsigned short)(v.z & 0xffff));
            a[5] += bf2f((unsigned short)(v.z >> 16));
            a[6] += bf2f((unsigned short)(v.w & 0xffff));
            a[7] += bf2f((unsigned short)(v.w >> 16));
        }
        uint4 o;
        o.x = (unsigned)f2bf(a[0]*0.1f) | ((unsigned)f2bf(a[1]*0.1f) << 16);
        o.y = (unsigned)f2bf(a[2]*0.1f) | ((unsigned)f2bf(a[3]*0.1f) << 16);
        o.z = (unsigned)f2bf(a[4]*0.1f) | ((unsigned)f2bf(a[5]*0.1f) << 16);
        o.w = (unsigned)f2bf(a[6]*0.1f) | ((unsigned)f2bf(a[7]*0.1f) << 16);
        *(uint4*)((unsigned short*)&X2[row * 264 + cg * 8]) = o;
    }
    __syncthreads();      // A buffers ready; K-loop is barrier-free from here

    f4v acc[2];
    acc[0] = (f4v){0.f, 0.f, 0.f, 0.f};
    acc[1] = (f4v){0.f, 0.f, 0.f, 0.f};

#pragma unroll
    for (int kc = 0; kc < 12; kc++) {
        const short* Ab = (kc < 4) ? Ah : (kc < 8) ? A1 : X2;
        int kl = (kc & 3) * 64;
#pragma unroll
        for (int ks = 0; ks < 2; ks++) {
            s8v a = *(const s8v*)(&Ab[l15 * 264 + kl + ks * 32 + quad * 8]);
#pragma unroll
            for (int f = 0; f < 2; f++) {
                // fragment-major B: one coalesced 1KB wave load
                s8v b = *(const s8v*)(Wt + ((kc * 2 + ks) * 16 + (w * 2 + f)) * 512 + lane * 8);
                acc[f] = __builtin_amdgcn_mfma_f32_16x16x32_bf16(a, b, acc[f], 0, 0, 0);
            }
        }
    }

    // ---- epilogue: Euler update + readout partials ---------------------------
    float py[4][3] = {};
#pragma unroll
    for (int f = 0; f < 2; f++) {
        int col = w * 32 + f * 16 + l15;
        float cbv = cbl[col];
        float rw0 = rwl[col * 3], rw1 = rwl[col * 3 + 1], rw2 = rwl[col * 3 + 2];
#pragma unroll
        for (int r = 0; r < 4; r++) {
            int grow = m0 + quad * 4 + r;
            float cval = acc[f][r] + cbv;
            float hn = hdo[grow * 256 + col] + EPSC * fast_tanh(cval);
            hdo[grow * 256 + col] = hn;
            hbf[grow * 256 + col] = f2bf(hn);
            py[r][0] += hn * rw0; py[r][1] += hn * rw1; py[r][2] += hn * rw2;
        }
    }
    for (int off = 1; off < 16; off <<= 1)
        for (int r = 0; r < 4; r++)
            for (int j = 0; j < 3; j++)
                py[r][j] += __shfl_xor(py[r][j], off, 64);
    if (l15 == 0)
        for (int r = 0; r < 4; r++)
            for (int j = 0; j < 3; j++)
                yred[w][quad][r][j] = py[r][j];
    __syncthreads();
    if (w == 0 && l15 == 0) {
        for (int r = 0; r < 4; r++) {
            int grow = m0 + quad * 4 + r;
            for (int j = 0; j < 3; j++) {
                float yv = rb[j];
                for (int ww = 0; ww < 8; ww++) yv += yred[ww][quad][r][j];
                yout[grow * 3 + j] = yv;
                if (yfin) yfin[grow * 3 + j] = yv;
            }
        }
    }
}

extern "C" void kernel_launch(void* const* d_in, const int* in_sizes, int n_in,
                              void* d_out, int out_size, void* d_ws, size_t ws_size,
                              hipStream_t stream) {
    const float* lm = (const float*)d_in[0];
    const float* ew = (const float*)d_in[1];
    const float* eb = (const float*)d_in[2];
    const float* rw = (const float*)d_in[3];
    const float* rb = (const float*)d_in[4];
    const float* cw = (const float*)d_in[5];
    const float* cb = (const float*)d_in[6];

    float* out = (float*)d_out;
    float* y_out = out;
    float* h_out = out + 24576;
    float* x_out = out + 24576 + 2097152;
    float* lp_out = x_out + 24576;

    char* ws = (char*)d_ws;
    int* nbr = (int*)ws;                       ws += NN * KNN * sizeof(int);
    float4* pos4 = (float4*)ws;                ws += NN * sizeof(float4);
    char* uni = ws;
    unsigned short* hbf = (unsigned short*)uni;
    unsigned short* x1  = hbf + NN * DH;
    unsigned short* Wt  = x1 + NN * DH;

    prep_pos<<<NN / 256, 256, 0, stream>>>(lm, pos4);
    knn_wave<<<NN / QPB, 1024, 0, stream>>>(lm, pos4, nbr);
    prep_wt<<<768, 256, 0, stream>>>(cw, Wt);
    emb_kernel<<<NN, 256, 0, stream>>>(lm, ew, eb, rw, rb, h_out, hbf, x_out);
    for (int t = 0; t < TSTEPS; t++) {
        agg_kernel<<<NN / 8, 256, 0, stream>>>(hbf, x1, nbr);
        gemm_step<<<NN / 16, 512, 0, stream>>>(hbf, x1, nbr, Wt, cb, rw, rb, h_out,
                                               lp_out + t * 24576,
                                               (t == TSTEPS - 1) ? y_out : nullptr);
    }
}

// Round 18
// 371.706 us; speedup vs baseline: 1.0483x; 1.0026x over previous
//
#include <hip/hip_runtime.h>
#include <float.h>
#include <math.h>

#define NN 8192
#define DH 256
#define KNN 10
#define TSTEPS 10
#define EPSC 0.1f
#define CTILE 1024          // candidates staged in LDS per tile
#define QPB 16              // queries per block (16 waves of 64)

typedef short s8v __attribute__((ext_vector_type(8)));
typedef float f4v __attribute__((ext_vector_type(4)));

__device__ __forceinline__ float bf2f(unsigned short u) {
    union { unsigned u; float f; } c; c.u = ((unsigned)u) << 16; return c.f;
}
__device__ __forceinline__ unsigned short f2bf(float f) {
    union { float f; unsigned u; } c; c.f = f;
    unsigned r = c.u + 0x7FFF + ((c.u >> 16) & 1);
    return (unsigned short)(r >> 16);
}

// fast tanh: (e^2x - 1)/(e^2x + 1) via v_exp_f32 + rcp. ~8 VALU vs ocml's
// ~25-50. |x| <~ 10 here (conv outputs), no overflow (needs |x|<44).
// Measured: -7us total (R16). abs err ~1e-6 -> negligible vs 0.1725 threshold.
__device__ __forceinline__ float fast_tanh(float x) {
    float t = __expf(2.0f * x);
    return __fdividef(t - 1.0f, t + 1.0f);
}

// -------- conv_ws [3][256][256] (k,n) -> FRAGMENT-MAJOR bf16 Wt ---------------
// frag = (kc*2+ks)*16 + nb. Lane layout matches the MFMA B operand exactly;
// a wave's B load = 1KB contiguous (fully coalesced), no LDS staging needed.
__global__ void prep_wt(const float* __restrict__ W, unsigned short* __restrict__ Wt) {
    int e = blockIdx.x * 256 + threadIdx.x;     // 768*256 = 196608
    int i8 = e & 7, lane = (e >> 3) & 63, nb = (e >> 9) & 15;
    int ks = (e >> 13) & 1, kc2 = (e >> 14) & 3, g = e >> 16;
    int quad = lane >> 4, l15 = lane & 15;
    int k = kc2 * 64 + ks * 32 + quad * 8 + i8;
    int n = nb * 16 + l15;
    Wt[e] = f2bf(W[g * 65536 + k * 256 + n]);
}

// ---------------- pos4[j] = {x, y, z, |p|^2} ----------------------------------
__global__ void prep_pos(const float* __restrict__ pos, float4* __restrict__ pos4) {
    int j = blockIdx.x * 256 + threadIdx.x;
    float x = pos[j * 3], y = pos[j * 3 + 1], z = pos[j * 3 + 2];
    float4 v; v.x = x; v.y = y; v.z = z; v.w = x * x + y * y + z * z;
    pos4[j] = v;
}

// ---------------- kNN: 1 wave/query, 16 queries/block, DPP-insert pops --------
// R14 version (~56us, structural floor for brute-force scan). Parked.
__launch_bounds__(1024)
__global__ void knn_wave(const float* __restrict__ pos, const float4* __restrict__ pos4,
                         int* __restrict__ nbr) {
    __shared__ float4 cand[CTILE];
    int tid = threadIdx.x;
    int wv = tid >> 6, lane = tid & 63;
    int i = blockIdx.x * QPB + wv;               // query for this wave
    float xi = pos[i * 3], yi = pos[i * 3 + 1], zi = pos[i * 3 + 2];
    float sqi = xi * xi + yi * yi + zi * zi;
    int igrp = i & ~63;                          // the only 64-group containing i

    float b  = FLT_MAX;                          // rank 'lane' distance
    int   ib = -1;                               // rank 'lane' index
    float thr = FLT_MAX;                         // batch-level 10th best bound

    for (int tile = 0; tile < NN / CTILE; ++tile) {
        __syncthreads();
        cand[tid] = pos4[tile * CTILE + tid];    // 1024 threads, 1 float4 each
        __syncthreads();
#pragma unroll 4
        for (int u = 0; u < CTILE / 64; ++u) {
            int jgrp = tile * CTILE + u * 64;
            float4 c = cand[u * 64 + lane];
            int j = jgrp + lane;
            float m = c.x * xi + c.y * yi + c.z * zi;
            float d = (sqi + c.w) - 2.0f * m;
            if (jgrp == igrp) {                  // wave-uniform branch
                if (j == i) d = FLT_MAX;         // self-exclusion, one batch only
            }
            unsigned long long mask = __ballot(d < thr);
            if (mask) {
                do {
                    int l = __ffsll((unsigned long long)mask) - 1;
                    mask &= mask - 1;
                    float dc = __int_as_float(__builtin_amdgcn_readlane(__float_as_int(d), l));
                    int jc = __builtin_amdgcn_readlane(j, l);
                    // shift-down neighbors via DPP row_shr:1 (lane r <- r-1)
                    float bp = __int_as_float(__builtin_amdgcn_update_dpp(
                        0, __float_as_int(b), 0x111, 0xF, 0xF, true));
                    int ip = __builtin_amdgcn_update_dpp(0, ib, 0x111, 0xF, 0xF, true);
                    bool c0 = dc < b;                    // insert at/below my rank
                    bool cp = (lane != 0) && (dc < bp);  // insert strictly below
                    b  = c0 ? (cp ? bp : dc) : b;
                    ib = c0 ? (cp ? ip : jc) : ib;
                } while (mask);
                thr = __int_as_float(__builtin_amdgcn_readlane(__float_as_int(b), 9));
            }
        }
    }
    if (lane < KNN) nbr[i * KNN + lane] = ib;    // rank r already in lane r
}

// ---------------- h = lm@emb_w + emb_b ; x = h@rw + rb ------------------------
__global__ void emb_kernel(const float* __restrict__ lm, const float* __restrict__ ew,
                           const float* __restrict__ eb, const float* __restrict__ rw,
                           const float* __restrict__ rb,
                           float* __restrict__ hdo, unsigned short* __restrict__ hbf,
                           float* __restrict__ xout) {
    __shared__ float s0[4], s1[4], s2[4];
    int i = blockIdx.x, d = threadIdx.x;
    float a0 = lm[i * 3], a1 = lm[i * 3 + 1], a2 = lm[i * 3 + 2];
    float h = eb[d] + a0 * ew[d] + a1 * ew[256 + d] + a2 * ew[512 + d];
    hdo[i * 256 + d] = h;
    hbf[i * 256 + d] = f2bf(h);
    float p0 = h * rw[d * 3], p1 = h * rw[d * 3 + 1], p2 = h * rw[d * 3 + 2];
    for (int off = 32; off; off >>= 1) {
        p0 += __shfl_down(p0, off, 64);
        p1 += __shfl_down(p1, off, 64);
        p2 += __shfl_down(p2, off, 64);
    }
    int lane = d & 63, wid = d >> 6;
    if (lane == 0) { s0[wid] = p0; s1[wid] = p1; s2[wid] = p2; }
    __syncthreads();
    if (d == 0) {
        xout[i * 3 + 0] = s0[0] + s0[1] + s0[2] + s0[3] + rb[0];
        xout[i * 3 + 1] = s1[0] + s1[1] + s1[2] + s1[3] + rb[1];
        xout[i * 3 + 2] = s2[0] + s2[1] + s2[2] + s2[3] + rb[2];
    }
}

// ---------------- hop-1: x1[i] = 0.1 * sum_{j in nbr(i)} hbf[j] ---------------
__global__ void agg_kernel(const unsigned short* __restrict__ src,
                           unsigned short* __restrict__ dst,
                           const int* __restrict__ nbr) {
    int tid = threadIdx.x;
    int slot = tid >> 5, l32 = tid & 31;
    int node = blockIdx.x * 8 + slot;
    int d0 = l32 * 8;
    const int* nb = nbr + node * KNN;
    int j[KNN];
#pragma unroll
    for (int q = 0; q < KNN; q++) j[q] = nb[q];
    uint4 v[KNN];
#pragma unroll
    for (int q = 0; q < KNN; q++) v[q] = *(const uint4*)(src + j[q] * 256 + d0);
    float a[8];
#pragma unroll
    for (int e = 0; e < 8; e++) a[e] = 0.f;
#pragma unroll
    for (int q = 0; q < KNN; q++) {
        a[0] += bf2f((unsigned short)(v[q].x & 0xffff));
        a[1] += bf2f((unsigned short)(v[q].x >> 16));
        a[2] += bf2f((unsigned short)(v[q].y & 0xffff));
        a[3] += bf2f((unsigned short)(v[q].y >> 16));
        a[4] += bf2f((unsigned short)(v[q].z & 0xffff));
        a[5] += bf2f((unsigned short)(v[q].z >> 16));
        a[6] += bf2f((unsigned short)(v[q].w & 0xffff));
        a[7] += bf2f((unsigned short)(v[q].w >> 16));
    }
    uint4 o;
    o.x = (unsigned)f2bf(a[0]*0.1f) | ((unsigned)f2bf(a[1]*0.1f) << 16);
    o.y = (unsigned)f2bf(a[2]*0.1f) | ((unsigned)f2bf(a[3]*0.1f) << 16);
    o.z = (unsigned)f2bf(a[4]*0.1f) | ((unsigned)f2bf(a[5]*0.1f) << 16);
    o.w = (unsigned)f2bf(a[6]*0.1f) | ((unsigned)f2bf(a[7]*0.1f) << 16);
    *(uint4*)(dst + node * 256 + d0) = o;
}

// ------- fused: hop-2 gather + BARRIER-FREE-K GEMM + Euler + readout ----------
// R16 exact (best verified composite, 372.7us): M16 x N256, 512 threads
// (8 waves), grid 512 = 2 blocks/CU = 4 waves/SIMD. B from fragment-major Wt
// (no LDS, no K-loop barriers; 2 barriers total). fast_tanh epilogue.
// R17's hdo-load hoist (semantically neutral per inspection) FAILED the
// harness (absmax 1.13) — do not reorder the epilogue hdo read.
__launch_bounds__(512, 4)
__global__ void gemm_step(unsigned short* hbf,
                          const unsigned short* __restrict__ x1,
                          const int* __restrict__ nbr,
                          const unsigned short* __restrict__ Wt,
                          const float* __restrict__ cb,
                          const float* __restrict__ rw, const float* __restrict__ rb,
                          float* hdo, float* __restrict__ yout, float* yfin) {
    __shared__ __align__(16) short Ah[16 * 264];
    __shared__ __align__(16) short A1[16 * 264];
    __shared__ __align__(16) short X2[16 * 264];
    __shared__ float rwl[768];
    __shared__ float cbl[256];
    __shared__ float yred[8][4][4][3];     // [wave][quad][r][xyz]

    int tid = threadIdx.x;
    int m0 = blockIdx.x * 16;
    for (int idx = tid; idx < 768; idx += 512) rwl[idx] = rw[idx];
    if (tid < 256) cbl[tid] = cb[tid];

    int w = tid >> 6, lane = tid & 63;
    int quad = lane >> 4, l15 = lane & 15;
    int row = tid >> 5, cg = tid & 31;            // stage coords: 16 rows x 32 thr

    // ---- stage A for hop0 (hbf) and hop1 (x1) --------------------------------
    {
        uint4 va = *(const uint4*)(((const unsigned short*)hbf) + (m0 + row) * 256 + cg * 8);
        *(uint4*)((unsigned short*)&Ah[row * 264 + cg * 8]) = va;
        uint4 vb = *(const uint4*)(x1 + (m0 + row) * 256 + cg * 8);
        *(uint4*)((unsigned short*)&A1[row * 264 + cg * 8]) = vb;
    }
    // ---- hop-2 gather: X2[row][:] = bf16(0.1 * sum x1[nbr[row]]) -------------
    {
        const int* nb = nbr + (m0 + row) * KNN;
        int j[KNN];
#pragma unroll
        for (int q = 0; q < KNN; q++) j[q] = nb[q];
        float a[8];
#pragma unroll
        for (int e = 0; e < 8; e++) a[e] = 0.f;
#pragma unroll
        for (int q = 0; q < KNN; q++) {
            uint4 v = *(const uint4*)(x1 + j[q] * 256 + cg * 8);
            a[0] += bf2f((unsigned short)(v.x & 0xffff));
            a[1] += bf2f((unsigned short)(v.x >> 16));
            a[2] += bf2f((unsigned short)(v.y & 0xffff));
            a[3] += bf2f((unsigned short)(v.y >> 16));
            a[4] += bf2f((unsigned short)(v.z & 0xffff));
            a[5] += bf2f((unsigned short)(v.z >> 16));
            a[6] += bf2f((unsigned short)(v.w & 0xffff));
            a[7] += bf2f((unsigned short)(v.w >> 16));
        }
        uint4 o;
        o.x = (unsigned)f2bf(a[0]*0.1f) | ((unsigned)f2bf(a[1]*0.1f) << 16);
        o.y = (unsigned)f2bf(a[2]*0.1f) | ((unsigned)f2bf(a[3]*0.1f) << 16);
        o.z = (unsigned)f2bf(a[4]*0.1f) | ((unsigned)f2bf(a[5]*0.1f) << 16);
        o.w = (unsigned)f2bf(a[6]*0.1f) | ((unsigned)f2bf(a[7]*0.1f) << 16);
        *(uint4*)((unsigned short*)&X2[row * 264 + cg * 8]) = o;
    }
    __syncthreads();      // A buffers ready; K-loop is barrier-free from here

    f4v acc[2];
    acc[0] = (f4v){0.f, 0.f, 0.f, 0.f};
    acc[1] = (f4v){0.f, 0.f, 0.f, 0.f};

#pragma unroll
    for (int kc = 0; kc < 12; kc++) {
        const short* Ab = (kc < 4) ? Ah : (kc < 8) ? A1 : X2;
        int kl = (kc & 3) * 64;
#pragma unroll
        for (int ks = 0; ks < 2; ks++) {
            s8v a = *(const s8v*)(&Ab[l15 * 264 + kl + ks * 32 + quad * 8]);
#pragma unroll
            for (int f = 0; f < 2; f++) {
                // fragment-major B: one coalesced 1KB wave load
                s8v b = *(const s8v*)(Wt + ((kc * 2 + ks) * 16 + (w * 2 + f)) * 512 + lane * 8);
                acc[f] = __builtin_amdgcn_mfma_f32_16x16x32_bf16(a, b, acc[f], 0, 0, 0);
            }
        }
    }

    // ---- epilogue: Euler update + readout partials ---------------------------
    float py[4][3] = {};
#pragma unroll
    for (int f = 0; f < 2; f++) {
        int col = w * 32 + f * 16 + l15;
        float cbv = cbl[col];
        float rw0 = rwl[col * 3], rw1 = rwl[col * 3 + 1], rw2 = rwl[col * 3 + 2];
#pragma unroll
        for (int r = 0; r < 4; r++) {
            int grow = m0 + quad * 4 + r;
            float cval = acc[f][r] + cbv;
            float hn = hdo[grow * 256 + col] + EPSC * fast_tanh(cval);
            hdo[grow * 256 + col] = hn;
            hbf[grow * 256 + col] = f2bf(hn);
            py[r][0] += hn * rw0; py[r][1] += hn * rw1; py[r][2] += hn * rw2;
        }
    }
    for (int off = 1; off < 16; off <<= 1)
        for (int r = 0; r < 4; r++)
            for (int j = 0; j < 3; j++)
                py[r][j] += __shfl_xor(py[r][j], off, 64);
    if (l15 == 0)
        for (int r = 0; r < 4; r++)
            for (int j = 0; j < 3; j++)
                yred[w][quad][r][j] = py[r][j];
    __syncthreads();
    if (w == 0 && l15 == 0) {
        for (int r = 0; r < 4; r++) {
            int grow = m0 + quad * 4 + r;
            for (int j = 0; j < 3; j++) {
                float yv = rb[j];
                for (int ww = 0; ww < 8; ww++) yv += yred[ww][quad][r][j];
                yout[grow * 3 + j] = yv;
                if (yfin) yfin[grow * 3 + j] = yv;
            }
        }
    }
}

extern "C" void kernel_launch(void* const* d_in, const int* in_sizes, int n_in,
                              void* d_out, int out_size, void* d_ws, size_t ws_size,
                              hipStream_t stream) {
    const float* lm = (const float*)d_in[0];
    const float* ew = (const float*)d_in[1];
    const float* eb = (const float*)d_in[2];
    const float* rw = (const float*)d_in[3];
    const float* rb = (const float*)d_in[4];
    const float* cw = (const float*)d_in[5];
    const float* cb = (const float*)d_in[6];

    float* out = (float*)d_out;
    float* y_out = out;
    float* h_out = out + 24576;
    float* x_out = out + 24576 + 2097152;
    float* lp_out = x_out + 24576;

    char* ws = (char*)d_ws;
    int* nbr = (int*)ws;                       ws += NN * KNN * sizeof(int);
    float4* pos4 = (float4*)ws;                ws += NN * sizeof(float4);
    char* uni = ws;
    unsigned short* hbf = (unsigned short*)uni;
    unsigned short* x1  = hbf + NN * DH;
    unsigned short* Wt  = x1 + NN * DH;

    prep_pos<<<NN / 256, 256, 0, stream>>>(lm, pos4);
    knn_wave<<<NN / QPB, 1024, 0, stream>>>(lm, pos4, nbr);
    prep_wt<<<768, 256, 0, stream>>>(cw, Wt);
    emb_kernel<<<NN, 256, 0, stream>>>(lm, ew, eb, rw, rb, h_out, hbf, x_out);
    for (int t = 0; t < TSTEPS; t++) {
        agg_kernel<<<NN / 8, 256, 0, stream>>>(hbf, x1, nbr);
        gemm_step<<<NN / 16, 512, 0, stream>>>(hbf, x1, nbr, Wt, cb, rw, rb, h_out,
                                               lp_out + t * 24576,
                                               (t == TSTEPS - 1) ? y_out : nullptr);
    }
}